// Round 15
// baseline (1819.441 us; speedup 1.0000x reference)
//
#include <hip/hip_runtime.h>

// ---------------------------------------------------------------------------
// multiStepModel: LSTM encoder (T=365) -> relu -> constant-input LSTM decoder
// (90 steps) -> relu -> FC.  Persistent cooperative kernel, 1 WG/CU.
// R15 = R14 (GB=8 x GJ=32, W-in-registers, split-f16 3-term MFMA, register
// cell, flag barrier) + SPECULATIVE h loads: every stored h word carries a
// step-parity bit (lo-f16 LSB, error ~2^-21 — R13-proven harmless); inside
// the barrier wait (after own flag publish) each WG speculatively loads next
// step's h; at loop top it parity-validates: all-fresh -> data RT is off the
// critical path (the straggler WG that gates the quorum is always all-fresh);
// any-stale -> one guaranteed-fresh reload (flags up => stores acked).
// ---------------------------------------------------------------------------

namespace {
constexpr int B = 128, T = 365, IN = 64, COV = 256, H = 512, OUTL = 90;
constexpr int GB = 8;            // batch groups (independent quorums)
constexpr int GJ = 32;           // hidden groups
constexpr int NWG = GB * GJ;     // 256 workgroups, 1/CU
constexpr int NT = 256;          // threads per WG (4 waves)
constexpr int BS = B / GB;       // 16 batch rows per WG
constexpr int HU = H / GJ;       // 16 hidden units per WG
constexpr int NR = 4 * HU;       // 64 gate rows per WG (row = unit*4 + gate)
constexpr int NSLOT_H = 64;      // 512/8 16B slots (h part of K)
constexpr int NSLOT = 72;        // + 64/8 slots (x part)
}

using ull = unsigned long long;
typedef __attribute__((ext_vector_type(8))) short short8;
typedef __attribute__((ext_vector_type(4))) short short4v;
typedef __attribute__((ext_vector_type(8))) _Float16 half8;
typedef __attribute__((ext_vector_type(4))) float f32x4;

__device__ unsigned int g_h[2][B][H];          // packed f16 (hi|lo, tagged)
__device__ float g_part[OUTL][GJ][B];          // per-hidden-group FC partials
__device__ __align__(256) int g_flag[GB][32];  // per-WG monotonic flags

__device__ __forceinline__ float sigfast(float x) {
  return __builtin_amdgcn_rcpf(1.0f + __expf(-x));
}
__device__ __forceinline__ float tanhfast(float x) {
  return 1.0f - 2.0f * __builtin_amdgcn_rcpf(__expf(2.0f * x) + 1.0f);
}

__device__ __forceinline__ float4 fma4(float4 a, float4 b, float4 c) {
  c.x = fmaf(a.x, b.x, c.x); c.y = fmaf(a.y, b.y, c.y);
  c.z = fmaf(a.z, b.z, c.z); c.w = fmaf(a.w, b.w, c.w);
  return c;
}

__device__ __forceinline__ unsigned int pack_split(float v) {
  _Float16 hi = (_Float16)v;
  _Float16 lo = (_Float16)(v - (float)hi);
  return ((unsigned int)__builtin_bit_cast(unsigned short, hi) << 16) |
         (unsigned int)__builtin_bit_cast(unsigned short, lo);
}
__device__ __forceinline__ float unpack_split(unsigned int u) {
  _Float16 hi = __builtin_bit_cast(_Float16, (unsigned short)(u >> 16));
  _Float16 lo = __builtin_bit_cast(_Float16, (unsigned short)(u & 0xFFFFu));
  return (float)hi + (float)lo;
}

// 8 consecutive fp32 -> f16 hi/lo fragment pair
__device__ __forceinline__ void cvt8(const float* src, half8& hi, half8& lo) {
  float4 p0 = ((const float4*)src)[0], p1 = ((const float4*)src)[1];
  float f[8] = {p0.x, p0.y, p0.z, p0.w, p1.x, p1.y, p1.z, p1.w};
#pragma unroll
  for (int j = 0; j < 8; ++j) {
    _Float16 h_ = (_Float16)f[j];
    hi[j] = h_;
    lo[j] = (_Float16)(f[j] - (float)h_);
  }
}

// Parity plan (continuous step counter; decoder sc = T + ot, T=365):
//   reader at step s:  buf s&1,      expects e = (s>>1)&1
//   writer at step s:  buf (s+1)&1,  stores  e = ((s+1)>>1)&1
// Buffer epochs alternate per write; k_init sets the complement of each
// buffer's first-read epoch: buf0 first read @s=2 expects 1 -> init 0;
// buf1 first read @s=1 expects 0 -> init 1.  Deterministic per launch.
__global__ void __launch_bounds__(256) k_init() {
  const int id = blockIdx.x * 256 + threadIdx.x;
  unsigned* h0 = &g_h[0][0][0];
  if (id < B * H) {
    h0[id] = 0u;
    h0[B * H + id] = 1u;
  }
  if (blockIdx.x == 0 && threadIdx.x < GB * 32)
    g_flag[threadIdx.x >> 5][threadIdx.x & 31] = 0;
}

__global__ void __launch_bounds__(NT, 1) k_lstm(
    const float* __restrict__ input, const float* __restrict__ covar,
    const float* __restrict__ W_ih1, const float* __restrict__ W_hh1,
    const float* __restrict__ b1,    const float* __restrict__ W_ih2,
    const float* __restrict__ W_hh2, const float* __restrict__ b2,
    const float* __restrict__ W_fc) {
  // B operand tiles (W register-resident).  Slot s of row r at s ^ (r&7).
  __shared__ __align__(16) short bH[BS][NSLOT * 8];   // [h;x] hi  18.4 KB
  __shared__ __align__(16) short bL[BS][NSLOT * 8];   // [h;x] lo  18.4 KB
  __shared__ float pb_lds[NR][17];                    // covproj+b1 / proj2
  __shared__ float aux[4][16];                        // decoder FC combine

  const int tid = threadIdx.x;
  const int gb  = blockIdx.x & (GB - 1);       // 0..7
  const int gj  = blockIdx.x >> 3;             // 0..31
  const int bg0 = gb * BS;
  const int j0  = gj * HU;

  const int lane  = tid & 63;
  const int wv    = tid >> 6;
  const int rows0 = wv * 16;               // gate-row tile (units wv*4..+3)
  const int ra    = rows0 + (lane & 15);   // A row (reordered gate row)
  const int b_l   = lane & 15;             // B row == D col == batch (shared)
  const int cc    = lane >> 4;             // k-chunk / gate-quad 0..3
  const int x7    = lane & 7;              // XOR swizzle key (== b_l&7)
  const int u_l   = wv * 4 + cc;           // this lane's unit 0..15

  const int bl  = tid >> 4;                // staging row 0..15
  const int sg  = tid & 15;                // staging phase 0..15
  const int bt  = tid & 15;                // fp32 helper: batch 0..15
  const int rt  = tid >> 4;                // fp32 helper: row base 0..15

  const int growA = (ra & 3) * H + j0 + (ra >> 2);   // lane's global W row

  // ---- loop-invariant W fragments in registers (R12-proven) ----
  half8 wA[16], wLo[16];     // h-part (K blocks 0..15)
  half8 xA[2],  xLo[2];      // x-part (encoder only)

  auto stage_whh_regs = [&](const float* Whh) {
    const float* base = Whh + (size_t)growA * H + cc * 8;
#pragma unroll
    for (int kb = 0; kb < 16; ++kb) cvt8(base + kb * 32, wA[kb], wLo[kb]);
  };

  // x staging: thread (bl, sg) covers float4 chunk sg of row bl (IN=64)
  auto load_x_regs = [&](int tn, float4& p) {
    p = *(const float4*)(input + ((size_t)(bg0 + bl) * T + tn) * IN + sg * 4);
  };
  auto stage_x_regs = [&](float4 p) {
    float f[4] = {p.x, p.y, p.z, p.w};
    short4v hi, lo;
#pragma unroll
    for (int j = 0; j < 4; ++j) {
      _Float16 h_ = (_Float16)f[j];
      hi[j] = __builtin_bit_cast(short, h_);
      lo[j] = __builtin_bit_cast(short, (_Float16)(f[j] - (float)h_));
    }
    const int s2 = (NSLOT_H + (sg >> 1)) ^ (bl & 7);
    *(short4v*)&bH[bl][s2 * 8 + (sg & 1) * 4] = hi;
    *(short4v*)&bL[bl][s2 * 8 + (sg & 1) * 4] = lo;
  };

  // h staging: dense 128B-coalesced LLC loads (16 ull/thread) + LDS commit
  ull spec[16];   // speculative h data, loaded inside the barrier wait
  auto load_h = [&](int par, ull (&tmp)[16]) {
    const ull* hr = (const ull*)&g_h[par][bg0 + bl][0];   // 256 ull per row
#pragma unroll
    for (int i = 0; i < 16; ++i)
      tmp[i] = __hip_atomic_load(hr + sg + 16 * i, __ATOMIC_RELAXED,
                                 __HIP_MEMORY_SCOPE_AGENT);
  };
  auto commit_h = [&](ull (&tmp)[16]) {
#pragma unroll
    for (int i = 0; i < 16; ++i) {
      const int m = sg + 16 * i;                 // ull index 0..255
      const int s2 = (m >> 2) ^ (bl & 7);        // swizzled 16B slot
      const int p = m & 3;                       // word within slot
      const unsigned u0 = (unsigned)tmp[i], u1 = (unsigned)(tmp[i] >> 32);
      ((unsigned*)&bH[bl][s2 * 8])[p] = (u0 >> 16) | (u1 & 0xFFFF0000u);
      ((unsigned*)&bL[bl][s2 * 8])[p] = (u0 & 0xFFFFu) | (u1 << 16);
    }
  };

  // ---- barrier: release sync + flag publish; SPECULATIVE h load for the
  // next step rides between publish and poll (spec_par < 0 = none).
  auto gbar = [&](int nb, bool with_x, float4 xp, int gp_ot, int spec_par) {
    __syncthreads();
    if (tid == 0)
      __hip_atomic_store(&g_flag[gb][gj], nb, __ATOMIC_RELAXED,
                         __HIP_MEMORY_SCOPE_AGENT);
    if (spec_par >= 0) load_h(spec_par, spec);
    if (with_x) stage_x_regs(xp);
    if (gp_ot >= 0 && tid < 16)   // decoder FC partial store (off crit path)
      g_part[gp_ot][gj][bg0 + tid] =
          aux[0][tid] + aux[1][tid] + aux[2][tid] + aux[3][tid];
    if (tid < 32) {
      while (__hip_atomic_load(&g_flag[gb][tid], __ATOMIC_RELAXED,
                               __HIP_MEMORY_SCOPE_AGENT) < nb)
        __builtin_amdgcn_s_sleep(1);
    }
    __syncthreads();
  };

  // validate speculative data (parity bit of both packed words == e);
  // stale -> reload (fresh guaranteed: flags up => all stores acked)
  auto validate_h = [&](int par, unsigned e) {
    unsigned bad = 0;
#pragma unroll
    for (int i = 0; i < 16; ++i)
      bad |= ((unsigned)spec[i] ^ e) | ((unsigned)(spec[i] >> 32) ^ e);
    if (bad & 1u) load_h(par, spec);
  };

  // tagged h' store: lo-LSB = step parity (error ~2^-21, R13-proven)
  auto store_h = [&](int wb, unsigned we, float hv) {
    const unsigned u = (pack_split(hv) & ~1u) | we;
    __hip_atomic_store(&g_h[wb][bg0 + b_l][j0 + u_l], u,
                       __ATOMIC_RELAXED, __HIP_MEMORY_SCOPE_AGENT);
  };

  // One MFMA k-block; A from registers, B from LDS.
  auto mfma_kb = [&](int kb, half8 ah, half8 al,
                     f32x4& aA, f32x4& aB, f32x4& aC) {
    const int s2 = (kb * 4 + cc) ^ x7;
    const half8 bh = __builtin_bit_cast(half8, *(const short8*)&bH[b_l][s2 * 8]);
    const half8 bo = __builtin_bit_cast(half8, *(const short8*)&bL[b_l][s2 * 8]);
    aA = __builtin_amdgcn_mfma_f32_16x16x32_f16(ah, bh, aA, 0, 0, 0);
    aB = __builtin_amdgcn_mfma_f32_16x16x32_f16(ah, bo, aB, 0, 0, 0);
    aC = __builtin_amdgcn_mfma_f32_16x16x32_f16(al, bh, aC, 0, 0, 0);
  };

  auto wrow = [&](int r) { return (r & 3) * H + j0 + (r >> 2); };

  // ======================= one-time setup =======================
  stage_whh_regs(W_hh1);
  {  // x-part W fragments (first IN=64 cols of W_ih1)
    const float* base = W_ih1 + (size_t)growA * (IN + COV) + cc * 8;
#pragma unroll
    for (int xk = 0; xk < 2; ++xk) cvt8(base + xk * 32, xA[xk], xLo[xk]);
  }
  {  // covariate projection + b1 -> pb_lds (fp32, once): 4 rows per thread
    const float4* cv = (const float4*)(covar + (size_t)(bg0 + bt) * COV);
    float accr[4] = {0.f, 0.f, 0.f, 0.f};
    const float4* wp[4];
#pragma unroll
    for (int rr = 0; rr < 4; ++rr)
      wp[rr] = (const float4*)(W_ih1 + (size_t)wrow(rt + rr * 16) * (IN + COV) + IN);
    for (int k = 0; k < COV / 4; ++k) {
      const float4 cvk = cv[k];
#pragma unroll
      for (int rr = 0; rr < 4; ++rr) {
        const float4 w = wp[rr][k];
        accr[rr] += cvk.x * w.x + cvk.y * w.y + cvk.z * w.z + cvk.w * w.w;
      }
    }
#pragma unroll
    for (int rr = 0; rr < 4; ++rr)
      pb_lds[rt + rr * 16][bt] = accr[rr] + b1[wrow(rt + rr * 16)];
  }
  {  // stage x_0
    float4 p;
    load_x_regs(0, p);
    stage_x_regs(p);
  }
  __syncthreads();   // pb_lds + x_0 ready

  float pb4[4];
#pragma unroll
  for (int q = 0; q < 4; ++q) pb4[q] = pb_lds[rows0 + cc * 4 + q][b_l];

  float c_state = 0.0f;

  auto cellp = [&](const f32x4& acc) -> float {
    const float gi = acc[0] + pb4[0];
    const float gf = acc[1] + pb4[1];
    const float gg = acc[2] + pb4[2];
    const float go = acc[3] + pb4[3];
    c_state = sigfast(gf) * c_state + sigfast(gi) * tanhfast(gg);
    return sigfast(go) * tanhfast(c_state);
  };

  // =================== encoder: 365 steps (step s = t) ===================
  for (int t = 0; t < T; ++t) {
    if (t > 0) validate_h(t & 1, (unsigned)((t >> 1) & 1));
    f32x4 aA = {0.f, 0.f, 0.f, 0.f}, aB = aA, aC = aA;
#pragma unroll
    for (int xk = 0; xk < 2; ++xk)             // x part (W in regs)
      mfma_kb(16 + xk, xA[xk], xLo[xk], aA, aB, aC);
    if (t > 0) commit_h(spec);                 // (reload flight overlapped)
    __syncthreads();                           // B h-tile ready for all waves
    if (t > 0) {
#pragma unroll
      for (int kb = 0; kb < 16; ++kb)
        mfma_kb(kb, wA[kb], wLo[kb], aA, aB, aC);   // h part (W in regs)
    }
    f32x4 acc;
#pragma unroll
    for (int q = 0; q < 4; ++q) acc[q] = aA[q] + aB[q] + aC[q];
    float hv = cellp(acc);
    if (t == T - 1) hv = fmaxf(hv, 0.0f);      // relu(h_enc)
    store_h((t + 1) & 1, (unsigned)(((t + 1) >> 1) & 1), hv);
    float4 xp = {0.f, 0.f, 0.f, 0.f};
    const bool havex = (t + 1 < T);
    if (havex) load_x_regs(t + 1, xp);
    gbar(t + 1, havex, xp, -1,
         (t + 1 < T) ? ((t + 1) & 1) : -1);    // spec-load h(t+1) in the wait
  }

  // ====== transition: proj2 = [relu(h_enc),covar] @ W_ih2^T + b2 (fp32) ======
  {
    const ull* hb = (const ull*)&g_h[1][bg0 + bt][0];   // h_enc (tagged, ok)
    const float* wr[4];
    float accr[4] = {0.f, 0.f, 0.f, 0.f};
#pragma unroll
    for (int rr = 0; rr < 4; ++rr)
      wr[rr] = W_ih2 + (size_t)wrow(rt + rr * 16) * (H + COV);
    for (int m = 0; m < H / 2; ++m) {   // h part from packed LLC state
      const ull v = __hip_atomic_load(hb + m, __ATOMIC_RELAXED,
                                      __HIP_MEMORY_SCOPE_AGENT);
      const float h0 = unpack_split((unsigned)v);
      const float h1 = unpack_split((unsigned)(v >> 32));
#pragma unroll
      for (int rr = 0; rr < 4; ++rr)
        accr[rr] += h0 * wr[rr][2 * m] + h1 * wr[rr][2 * m + 1];
    }
    {  // covar part (fp32, cache-hot)
      const float4* cv = (const float4*)(covar + (size_t)(bg0 + bt) * COV);
      for (int k = 0; k < COV / 4; ++k) {
        const float4 cvk = cv[k];
#pragma unroll
        for (int rr = 0; rr < 4; ++rr) {
          const float4 w = ((const float4*)wr[rr])[H / 4 + k];
          accr[rr] += cvk.x * w.x + cvk.y * w.y + cvk.z * w.z + cvk.w * w.w;
        }
      }
    }
#pragma unroll
    for (int rr = 0; rr < 4; ++rr)
      pb_lds[rt + rr * 16][bt] = accr[rr] + b2[wrow(rt + rr * 16)];
  }
  stage_whh_regs(W_hh2);        // decoder recurrent W -> registers
  c_state = 0.0f;
  {
    float4 dummy = {0.f, 0.f, 0.f, 0.f};
    gbar(T + 1, false, dummy, -1, -1);   // h_enc reads done (no spec: next
  }                                      // read needs decoder step-0 output

#pragma unroll
  for (int q = 0; q < 4; ++q) pb4[q] = pb_lds[rows0 + cc * 4 + q][b_l];
  const float wfc = W_fc[j0 + u_l];

  // ===== decoder: 90 steps (step s = T + ot; ot=0 writes buf0, preserving
  // h_enc in buf1 until everyone passed the transition barrier) =====
  for (int ot = 0; ot < OUTL; ++ot) {
    const int sc = T + ot;
    if (ot > 0) validate_h(sc & 1, (unsigned)((sc >> 1) & 1));
    if (ot > 0) commit_h(spec);
    __syncthreads();
    f32x4 aA = {0.f, 0.f, 0.f, 0.f}, aB = aA, aC = aA;
    if (ot > 0) {
#pragma unroll
      for (int kb = 0; kb < 16; ++kb)
        mfma_kb(kb, wA[kb], wLo[kb], aA, aB, aC);
    }
    f32x4 acc;
#pragma unroll
    for (int q = 0; q < 4; ++q) acc[q] = aA[q] + aB[q] + aC[q];
    const float hv = cellp(acc);             // ot==0: gates = proj2 only
    store_h((sc + 1) & 1, (unsigned)(((sc + 1) >> 1) & 1), hv);
    // FC partial: relu(hv)*wfc; sum over cc quads then over waves via aux
    float fcv = fmaxf(hv, 0.0f) * wfc;
    fcv += __shfl_xor(fcv, 16);
    fcv += __shfl_xor(fcv, 32);              // sum over the 4 unit-lanes
    if (lane < 16) aux[wv][lane] = fcv;
    float4 dummy = {0.f, 0.f, 0.f, 0.f};
    gbar(T + 2 + ot, false, dummy, ot,
         (ot + 1 < OUTL) ? ((sc + 1) & 1) : -1);   // spec + g_part in wait
  }
}

__global__ void __launch_bounds__(256) k_reduce(const float* __restrict__ b_fc,
                                                float* __restrict__ out) {
  int id = blockIdx.x * 256 + threadIdx.x;
  if (id >= B * OUTL) return;
  int b = id / OUTL, ot = id - b * OUTL;
  float s = b_fc[0];
#pragma unroll 8
  for (int g = 0; g < GJ; ++g) s += g_part[ot][g][b];
  out[id] = s;   // out[b][ot], row-major == id
}

extern "C" void kernel_launch(void* const* d_in, const int* in_sizes, int n_in,
                              void* d_out, int out_size, void* d_ws, size_t ws_size,
                              hipStream_t stream) {
  (void)in_sizes; (void)n_in; (void)d_ws; (void)ws_size; (void)out_size;
  const float* input = (const float*)d_in[0];
  const float* covar = (const float*)d_in[1];
  const float* W_ih1 = (const float*)d_in[2];
  const float* W_hh1 = (const float*)d_in[3];
  const float* b1    = (const float*)d_in[4];
  const float* W_ih2 = (const float*)d_in[5];
  const float* W_hh2 = (const float*)d_in[6];
  const float* b2    = (const float*)d_in[7];
  const float* W_fc  = (const float*)d_in[8];
  const float* b_fc  = (const float*)d_in[9];

  k_init<<<dim3((B * H + 255) / 256), dim3(256), 0, stream>>>();
  k_lstm<<<dim3(NWG), dim3(NT), 0, stream>>>(input, covar, W_ih1, W_hh1, b1,
                                             W_ih2, W_hh2, b2, W_fc);
  k_reduce<<<dim3((B * OUTL + 255) / 256), dim3(256), 0, stream>>>(
      b_fc, (float*)d_out);
}

// Round 16
// 1386.159 us; speedup vs baseline: 1.3126x; 1.3126x over previous
//
#include <hip/hip_runtime.h>

// ---------------------------------------------------------------------------
// multiStepModel: LSTM encoder (T=365) -> relu -> constant-input LSTM decoder
// (90 steps) -> relu -> FC.  Persistent cooperative kernel, 1 WG/CU.
// R16 = R14 (best: GB=8 x GJ=32, W-in-registers, split-f16 3-term MFMA,
// register cell, flag barrier, dense-coalesced LLC h staging) + ull-PAIRED
// h loads/commits: pairs land in the same swizzled 16B LDS slot at adjacent
// words -> ds_write_b64 (LDS write instrs halved, conflicts reduced).
// Protocol and everything else R14-verbatim.
// ---------------------------------------------------------------------------

namespace {
constexpr int B = 128, T = 365, IN = 64, COV = 256, H = 512, OUTL = 90;
constexpr int GB = 8;            // batch groups (independent quorums)
constexpr int GJ = 32;           // hidden groups
constexpr int NWG = GB * GJ;     // 256 workgroups, 1/CU
constexpr int NT = 256;          // threads per WG (4 waves)
constexpr int BS = B / GB;       // 16 batch rows per WG
constexpr int HU = H / GJ;       // 16 hidden units per WG
constexpr int NR = 4 * HU;       // 64 gate rows per WG (row = unit*4 + gate)
constexpr int NSLOT_H = 64;      // 512/8 16B slots (h part of K)
constexpr int NSLOT = 72;        // + 64/8 slots (x part)
}

using ull = unsigned long long;
typedef __attribute__((ext_vector_type(8))) short short8;
typedef __attribute__((ext_vector_type(4))) short short4v;
typedef __attribute__((ext_vector_type(8))) _Float16 half8;
typedef __attribute__((ext_vector_type(4))) float f32x4;

__device__ unsigned int g_h[2][B][H];          // packed f16 (hi<<16|lo) state
__device__ float g_part[OUTL][GJ][B];          // per-hidden-group FC partials
__device__ __align__(256) int g_flag[GB][32];  // per-WG monotonic flags

__device__ __forceinline__ float sigfast(float x) {
  return __builtin_amdgcn_rcpf(1.0f + __expf(-x));
}
__device__ __forceinline__ float tanhfast(float x) {
  return 1.0f - 2.0f * __builtin_amdgcn_rcpf(__expf(2.0f * x) + 1.0f);
}

__device__ __forceinline__ unsigned int pack_split(float v) {
  _Float16 hi = (_Float16)v;
  _Float16 lo = (_Float16)(v - (float)hi);
  return ((unsigned int)__builtin_bit_cast(unsigned short, hi) << 16) |
         (unsigned int)__builtin_bit_cast(unsigned short, lo);
}
__device__ __forceinline__ float unpack_split(unsigned int u) {
  _Float16 hi = __builtin_bit_cast(_Float16, (unsigned short)(u >> 16));
  _Float16 lo = __builtin_bit_cast(_Float16, (unsigned short)(u & 0xFFFFu));
  return (float)hi + (float)lo;
}

// 8 consecutive fp32 -> f16 hi/lo fragment pair
__device__ __forceinline__ void cvt8(const float* src, half8& hi, half8& lo) {
  float4 p0 = ((const float4*)src)[0], p1 = ((const float4*)src)[1];
  float f[8] = {p0.x, p0.y, p0.z, p0.w, p1.x, p1.y, p1.z, p1.w};
#pragma unroll
  for (int j = 0; j < 8; ++j) {
    _Float16 h_ = (_Float16)f[j];
    hi[j] = h_;
    lo[j] = (_Float16)(f[j] - (float)h_);
  }
}

__global__ void __launch_bounds__(256) k_init() {
  int t = threadIdx.x;
  if (t < GB * 32) g_flag[t >> 5][t & 31] = 0;
}

__global__ void __launch_bounds__(NT, 1) k_lstm(
    const float* __restrict__ input, const float* __restrict__ covar,
    const float* __restrict__ W_ih1, const float* __restrict__ W_hh1,
    const float* __restrict__ b1,    const float* __restrict__ W_ih2,
    const float* __restrict__ W_hh2, const float* __restrict__ b2,
    const float* __restrict__ W_fc) {
  // B operand tiles (W register-resident).  Slot s of row r at s ^ (r&7).
  __shared__ __align__(16) short bH[BS][NSLOT * 8];   // [h;x] hi  18.4 KB
  __shared__ __align__(16) short bL[BS][NSLOT * 8];   // [h;x] lo  18.4 KB
  __shared__ float pb_lds[NR][17];                    // covproj+b1 / proj2
  __shared__ float aux[4][16];                        // decoder FC combine

  const int tid = threadIdx.x;
  const int gb  = blockIdx.x & (GB - 1);       // 0..7
  const int gj  = blockIdx.x >> 3;             // 0..31
  const int bg0 = gb * BS;
  const int j0  = gj * HU;

  const int lane  = tid & 63;
  const int wv    = tid >> 6;
  const int rows0 = wv * 16;               // gate-row tile (units wv*4..+3)
  const int ra    = rows0 + (lane & 15);   // A row (reordered gate row)
  const int b_l   = lane & 15;             // B row == D col == batch (shared)
  const int cc    = lane >> 4;             // k-chunk / gate-quad 0..3
  const int x7    = lane & 7;              // XOR swizzle key (== b_l&7)
  const int u_l   = wv * 4 + cc;           // this lane's unit 0..15

  const int bl  = tid >> 4;                // staging row 0..15
  const int sg  = tid & 15;                // staging phase 0..15
  const int bt  = tid & 15;                // fp32 helper: batch 0..15
  const int rt  = tid >> 4;                // fp32 helper: row base 0..15

  const int growA = (ra & 3) * H + j0 + (ra >> 2);   // lane's global W row

  // ---- loop-invariant W fragments in registers (R12-proven) ----
  half8 wA[16], wLo[16];     // h-part (K blocks 0..15)
  half8 xA[2],  xLo[2];      // x-part (encoder only)

  auto stage_whh_regs = [&](const float* Whh) {
    const float* base = Whh + (size_t)growA * H + cc * 8;
#pragma unroll
    for (int kb = 0; kb < 16; ++kb) cvt8(base + kb * 32, wA[kb], wLo[kb]);
  };

  // x staging: thread (bl, sg) covers float4 chunk sg of row bl (IN=64)
  auto load_x_regs = [&](int tn, float4& p) {
    p = *(const float4*)(input + ((size_t)(bg0 + bl) * T + tn) * IN + sg * 4);
  };
  auto stage_x_regs = [&](float4 p) {
    float f[4] = {p.x, p.y, p.z, p.w};
    short4v hi, lo;
#pragma unroll
    for (int j = 0; j < 4; ++j) {
      _Float16 h_ = (_Float16)f[j];
      hi[j] = __builtin_bit_cast(short, h_);
      lo[j] = __builtin_bit_cast(short, (_Float16)(f[j] - (float)h_));
    }
    const int s2 = (NSLOT_H + (sg >> 1)) ^ (bl & 7);
    *(short4v*)&bH[bl][s2 * 8 + (sg & 1) * 4] = hi;
    *(short4v*)&bL[bl][s2 * 8 + (sg & 1) * 4] = lo;
  };

  // ---- R14-proven barrier (quorum 32).  Release: __syncthreads (drains
  // vmcnt) + one relaxed-AGENT flag store.  Poll: lane i watches member i.
  auto gbar = [&](int nb, bool with_x, float4 xp, int gp_ot) {
    __syncthreads();
    if (tid == 0)
      __hip_atomic_store(&g_flag[gb][gj], nb, __ATOMIC_RELAXED,
                         __HIP_MEMORY_SCOPE_AGENT);
    if (with_x) stage_x_regs(xp);
    if (gp_ot >= 0 && tid < 16)   // decoder FC partial store (off crit path)
      g_part[gp_ot][gj][bg0 + tid] =
          aux[0][tid] + aux[1][tid] + aux[2][tid] + aux[3][tid];
    if (tid < 32) {
      while (__hip_atomic_load(&g_flag[gb][tid], __ATOMIC_RELAXED,
                               __HIP_MEMORY_SCOPE_AGENT) < nb)
        __builtin_amdgcn_s_sleep(1);
    }
    __syncthreads();
  };

  // h staging: dense PAIRED LLC loads (thread (bl,sg): ulls 2sg+32i+d ->
  // 256B contiguous per 16 lanes) + ds_write_b64 commits (pair lands at
  // adjacent words of ONE swizzled 16B slot).
  auto load_h = [&](int par, ull (&tmp)[16]) {
    const ull* hr = (const ull*)&g_h[par][bg0 + bl][0];   // 256 ull per row
#pragma unroll
    for (int i = 0; i < 8; ++i) {
      tmp[2 * i]     = __hip_atomic_load(hr + 2 * sg + 32 * i, __ATOMIC_RELAXED,
                                         __HIP_MEMORY_SCOPE_AGENT);
      tmp[2 * i + 1] = __hip_atomic_load(hr + 2 * sg + 32 * i + 1,
                                         __ATOMIC_RELAXED,
                                         __HIP_MEMORY_SCOPE_AGENT);
    }
  };
  auto commit_h = [&](ull (&tmp)[16]) {
#pragma unroll
    for (int i = 0; i < 8; ++i) {
      const int m0 = 2 * sg + 32 * i;            // even ull index
      const int s2 = (m0 >> 2) ^ (bl & 7);       // swizzled 16B slot
      const int pd = (m0 & 3) >> 1;              // ull word within slot (0/1)
      ull hiP = 0, loP = 0;
#pragma unroll
      for (int d = 0; d < 2; ++d) {
        const unsigned u0 = (unsigned)tmp[2 * i + d];
        const unsigned u1 = (unsigned)(tmp[2 * i + d] >> 32);
        const unsigned hw = (u0 >> 16) | (u1 & 0xFFFF0000u);
        const unsigned lw = (u0 & 0xFFFFu) | (u1 << 16);
        hiP |= (ull)hw << (32 * d);
        loP |= (ull)lw << (32 * d);
      }
      ((ull*)&bH[bl][s2 * 8])[pd] = hiP;         // ds_write_b64
      ((ull*)&bL[bl][s2 * 8])[pd] = loP;         // ds_write_b64
    }
  };

  // One MFMA k-block; A from registers, B from LDS.
  auto mfma_kb = [&](int kb, half8 ah, half8 al,
                     f32x4& aA, f32x4& aB, f32x4& aC) {
    const int s2 = (kb * 4 + cc) ^ x7;
    const half8 bh = __builtin_bit_cast(half8, *(const short8*)&bH[b_l][s2 * 8]);
    const half8 bo = __builtin_bit_cast(half8, *(const short8*)&bL[b_l][s2 * 8]);
    aA = __builtin_amdgcn_mfma_f32_16x16x32_f16(ah, bh, aA, 0, 0, 0);
    aB = __builtin_amdgcn_mfma_f32_16x16x32_f16(ah, bo, aB, 0, 0, 0);
    aC = __builtin_amdgcn_mfma_f32_16x16x32_f16(al, bh, aC, 0, 0, 0);
  };

  auto wrow = [&](int r) { return (r & 3) * H + j0 + (r >> 2); };

  // ======================= one-time setup =======================
  stage_whh_regs(W_hh1);
  {  // x-part W fragments (first IN=64 cols of W_ih1)
    const float* base = W_ih1 + (size_t)growA * (IN + COV) + cc * 8;
#pragma unroll
    for (int xk = 0; xk < 2; ++xk) cvt8(base + xk * 32, xA[xk], xLo[xk]);
  }
  {  // covariate projection + b1 -> pb_lds (fp32, once): 4 rows per thread
    const float4* cv = (const float4*)(covar + (size_t)(bg0 + bt) * COV);
    float accr[4] = {0.f, 0.f, 0.f, 0.f};
    const float4* wp[4];
#pragma unroll
    for (int rr = 0; rr < 4; ++rr)
      wp[rr] = (const float4*)(W_ih1 + (size_t)wrow(rt + rr * 16) * (IN + COV) + IN);
    for (int k = 0; k < COV / 4; ++k) {
      const float4 cvk = cv[k];
#pragma unroll
      for (int rr = 0; rr < 4; ++rr) {
        const float4 w = wp[rr][k];
        accr[rr] += cvk.x * w.x + cvk.y * w.y + cvk.z * w.z + cvk.w * w.w;
      }
    }
#pragma unroll
    for (int rr = 0; rr < 4; ++rr)
      pb_lds[rt + rr * 16][bt] = accr[rr] + b1[wrow(rt + rr * 16)];
  }
  {  // stage x_0
    float4 p;
    load_x_regs(0, p);
    stage_x_regs(p);
  }
  __syncthreads();   // pb_lds + x_0 ready

  float pb4[4];
#pragma unroll
  for (int q = 0; q < 4; ++q) pb4[q] = pb_lds[rows0 + cc * 4 + q][b_l];

  float c_state = 0.0f;

  auto cellp = [&](const f32x4& acc) -> float {
    const float gi = acc[0] + pb4[0];
    const float gf = acc[1] + pb4[1];
    const float gg = acc[2] + pb4[2];
    const float go = acc[3] + pb4[3];
    c_state = sigfast(gf) * c_state + sigfast(gi) * tanhfast(gg);
    return sigfast(go) * tanhfast(c_state);
  };

  // =================== encoder: 365 steps ===================
  for (int t = 0; t < T; ++t) {
    ull tmp[16];
    if (t > 0) load_h(t & 1, tmp);             // issue 16 LLC loads
    f32x4 aA = {0.f, 0.f, 0.f, 0.f}, aB = aA, aC = aA;
#pragma unroll
    for (int xk = 0; xk < 2; ++xk)             // x part (W in regs)
      mfma_kb(16 + xk, xA[xk], xLo[xk], aA, aB, aC);
    if (t > 0) commit_h(tmp);                  // (overlapped load flight)
    __syncthreads();                           // B h-tile ready for all waves
    if (t > 0) {
#pragma unroll
      for (int kb = 0; kb < 16; ++kb)
        mfma_kb(kb, wA[kb], wLo[kb], aA, aB, aC);   // h part (W in regs)
    }
    f32x4 acc;
#pragma unroll
    for (int q = 0; q < 4; ++q) acc[q] = aA[q] + aB[q] + aC[q];
    float hv = cellp(acc);
    if (t == T - 1) hv = fmaxf(hv, 0.0f);      // relu(h_enc)
    __hip_atomic_store(&g_h[(t + 1) & 1][bg0 + b_l][j0 + u_l], pack_split(hv),
                       __ATOMIC_RELAXED, __HIP_MEMORY_SCOPE_AGENT);
    float4 xp = {0.f, 0.f, 0.f, 0.f};
    const bool havex = (t + 1 < T);
    if (havex) load_x_regs(t + 1, xp);
    gbar(t + 1, havex, xp, -1);                // stage x_{t+1} in the wait
  }

  // ====== transition: proj2 = [relu(h_enc),covar] @ W_ih2^T + b2 (fp32) ======
  {
    const ull* hb = (const ull*)&g_h[1][bg0 + bt][0];
    const float* wr[4];
    float accr[4] = {0.f, 0.f, 0.f, 0.f};
#pragma unroll
    for (int rr = 0; rr < 4; ++rr)
      wr[rr] = W_ih2 + (size_t)wrow(rt + rr * 16) * (H + COV);
    for (int m = 0; m < H / 2; ++m) {   // h part from packed LLC state
      const ull v = __hip_atomic_load(hb + m, __ATOMIC_RELAXED,
                                      __HIP_MEMORY_SCOPE_AGENT);
      const float h0 = unpack_split((unsigned)v);
      const float h1 = unpack_split((unsigned)(v >> 32));
#pragma unroll
      for (int rr = 0; rr < 4; ++rr)
        accr[rr] += h0 * wr[rr][2 * m] + h1 * wr[rr][2 * m + 1];
    }
    {  // covar part (fp32, cache-hot)
      const float4* cv = (const float4*)(covar + (size_t)(bg0 + bt) * COV);
      for (int k = 0; k < COV / 4; ++k) {
        const float4 cvk = cv[k];
#pragma unroll
        for (int rr = 0; rr < 4; ++rr) {
          const float4 w = ((const float4*)wr[rr])[H / 4 + k];
          accr[rr] += cvk.x * w.x + cvk.y * w.y + cvk.z * w.z + cvk.w * w.w;
        }
      }
    }
#pragma unroll
    for (int rr = 0; rr < 4; ++rr)
      pb_lds[rt + rr * 16][bt] = accr[rr] + b2[wrow(rt + rr * 16)];
  }
  stage_whh_regs(W_hh2);        // decoder recurrent W -> registers
  c_state = 0.0f;
  {
    float4 dummy = {0.f, 0.f, 0.f, 0.f};
    gbar(T + 1, false, dummy, -1);   // protects g_h[1] reads vs ot=0 write
  }

#pragma unroll
  for (int q = 0; q < 4; ++q) pb4[q] = pb_lds[rows0 + cc * 4 + q][b_l];
  const float wfc = W_fc[j0 + u_l];

  // =================== decoder: 90 steps ===================
  for (int ot = 0; ot < OUTL; ++ot) {
    if (ot > 0) {
      ull tmp[16];
      load_h(ot & 1, tmp);
      commit_h(tmp);
    }
    __syncthreads();
    f32x4 aA = {0.f, 0.f, 0.f, 0.f}, aB = aA, aC = aA;
    if (ot > 0) {
#pragma unroll
      for (int kb = 0; kb < 16; ++kb)
        mfma_kb(kb, wA[kb], wLo[kb], aA, aB, aC);
    }
    f32x4 acc;
#pragma unroll
    for (int q = 0; q < 4; ++q) acc[q] = aA[q] + aB[q] + aC[q];
    const float hv = cellp(acc);             // ot==0: gates = proj2 only
    __hip_atomic_store(&g_h[(ot + 1) & 1][bg0 + b_l][j0 + u_l], pack_split(hv),
                       __ATOMIC_RELAXED, __HIP_MEMORY_SCOPE_AGENT);
    // FC partial: relu(hv)*wfc; sum over cc quads then over waves via aux
    float fcv = fmaxf(hv, 0.0f) * wfc;
    fcv += __shfl_xor(fcv, 16);
    fcv += __shfl_xor(fcv, 32);              // sum over the 4 unit-lanes
    if (lane < 16) aux[wv][lane] = fcv;
    float4 dummy = {0.f, 0.f, 0.f, 0.f};
    gbar(T + 2 + ot, false, dummy, ot);      // g_part store rides the wait
  }
}

__global__ void __launch_bounds__(256) k_reduce(const float* __restrict__ b_fc,
                                                float* __restrict__ out) {
  int id = blockIdx.x * 256 + threadIdx.x;
  if (id >= B * OUTL) return;
  int b = id / OUTL, ot = id - b * OUTL;
  float s = b_fc[0];
#pragma unroll 8
  for (int g = 0; g < GJ; ++g) s += g_part[ot][g][b];
  out[id] = s;   // out[b][ot], row-major == id
}

extern "C" void kernel_launch(void* const* d_in, const int* in_sizes, int n_in,
                              void* d_out, int out_size, void* d_ws, size_t ws_size,
                              hipStream_t stream) {
  (void)in_sizes; (void)n_in; (void)d_ws; (void)ws_size; (void)out_size;
  const float* input = (const float*)d_in[0];
  const float* covar = (const float*)d_in[1];
  const float* W_ih1 = (const float*)d_in[2];
  const float* W_hh1 = (const float*)d_in[3];
  const float* b1    = (const float*)d_in[4];
  const float* W_ih2 = (const float*)d_in[5];
  const float* W_hh2 = (const float*)d_in[6];
  const float* b2    = (const float*)d_in[7];
  const float* W_fc  = (const float*)d_in[8];
  const float* b_fc  = (const float*)d_in[9];

  k_init<<<dim3(1), dim3(256), 0, stream>>>();
  k_lstm<<<dim3(NWG), dim3(NT), 0, stream>>>(input, covar, W_ih1, W_hh1, b1,
                                             W_ih2, W_hh2, b2, W_fc);
  k_reduce<<<dim3((B * OUTL + 255) / 256), dim3(256), 0, stream>>>(
      b_fc, (float*)d_out);
}